// Round 1
// baseline (1025.185 us; speedup 1.0000x reference)
//
#include <hip/hip_runtime.h>
#include <hip/hip_bf16.h>

typedef __attribute__((ext_vector_type(8))) short s16x8;
typedef __attribute__((ext_vector_type(4))) short s16x4;
typedef __attribute__((ext_vector_type(4))) float f32x4;

#define T_TOK 4096
#define DMODEL 2048
#define ISH 4096
#define IMOE 2048
#define NEXP 16
#define PADMAX 10240
#define MAXTILES 80

// ---- workspace layout (bytes) ----
#define XB_OFF   ((size_t)0)                          // ushort[T_TOK*DMODEL] = 16 MB
#define H_OFF    ((size_t)T_TOK*DMODEL*2)             // H: ushort, max(T*ISH, PADMAX*IMOE)
#define H_BYTES  ((size_t)PADMAX*IMOE*2)              // 41,943,040
#define Y_OFF    (H_OFF + H_BYTES)
#define Y_BYTES  ((size_t)2*T_TOK*DMODEL*4)           // 67 MB
#define C_OFF    (Y_OFF + Y_BYTES)
// control block offsets (bytes from C_OFF)
#define CNT_OFF    0
#define OFF_OFF    64
#define CUR_OFF    192
#define TILEE_OFF  256
#define TKI_OFF    1024
#define TKW_OFF    (TKI_OFF + T_TOK*2*4)
#define LCODE_OFF  (TKW_OFF + T_TOK*2*4)
#define LW_OFF     (LCODE_OFF + PADMAX*4)

__device__ __forceinline__ unsigned short f2bf(float f) {
    union { float f; unsigned u; } c; c.f = f;
    unsigned u = c.u;
    u += 0x7fffu + ((u >> 16) & 1u);   // RNE
    return (unsigned short)(u >> 16);
}

// ---- cast x (fp32) -> xb (bf16) ----
__global__ void cvt_x_kernel(const float* __restrict__ x, unsigned short* __restrict__ xb) {
    size_t i = (size_t)blockIdx.x * 256 + threadIdx.x;   // 2,097,152 float4 chunks
    float4 v = ((const float4*)x)[i];
    s16x4 o;
    o[0] = (short)f2bf(v.x); o[1] = (short)f2bf(v.y);
    o[2] = (short)f2bf(v.z); o[3] = (short)f2bf(v.w);
    ((s16x4*)xb)[i] = o;
}

// ---- gate: fp64 logits, softmax top-2 renorm, counts ----
__global__ void gate_kernel(const float* __restrict__ x, const float* __restrict__ wg,
                            int* __restrict__ tki, float* __restrict__ tkw, int* __restrict__ cnt) {
    int t = blockIdx.x;
    __shared__ float xs[DMODEL];
    __shared__ float lg[NEXP];
    const float* xr = x + (size_t)t * DMODEL;
    for (int i = threadIdx.x; i < DMODEL; i += 256) xs[i] = xr[i];
    __syncthreads();
    int g = threadIdx.x >> 4, l = threadIdx.x & 15;
    const float* w = wg + (size_t)g * DMODEL;
    double s = 0.0;
    for (int i = l; i < DMODEL; i += 16) s += (double)xs[i] * (double)w[i];
    for (int m = 8; m >= 1; m >>= 1) s += __shfl_xor(s, m, 64);
    if (l == 0) lg[g] = (float)s;
    __syncthreads();
    if (threadIdx.x == 0) {
        float v0 = -1e30f, v1 = -1e30f; int i0 = 0, i1 = 0;
        for (int e = 0; e < NEXP; e++) {
            float v = lg[e];
            if (v > v0) { v1 = v0; i1 = i0; v0 = v; i0 = e; }
            else if (v > v1) { v1 = v; i1 = e; }
        }
        // softmax over all then renorm top-2 == softmax over top-2 logits
        float w0 = 1.f / (1.f + expf(v1 - v0));
        float w1 = 1.f - w0;
        tki[t*2] = i0; tki[t*2+1] = i1;
        tkw[t*2] = w0; tkw[t*2+1] = w1;
        atomicAdd(&cnt[i0], 1); atomicAdd(&cnt[i1], 1);
    }
}

// ---- scan: 128-aligned offsets, tile->expert map, dummy fill ----
__global__ void scan_kernel(const int* __restrict__ cnt, int* __restrict__ off,
                            int* __restrict__ cur, int* __restrict__ tile_e,
                            int* __restrict__ lcode) {
    __shared__ int soff[17];
    if (threadIdx.x == 0) {
        int o = 0;
        for (int e = 0; e < NEXP; e++) {
            soff[e] = o; off[e] = o; cur[e] = 0;
            o += (cnt[e] + 127) & ~127;
        }
        soff[16] = o; off[16] = o;
    }
    __syncthreads();
    int ntiles = soff[16] >> 7;
    for (int i = threadIdx.x; i < MAXTILES; i += 256) {
        int e = -1;
        if (i < ntiles) {
            for (int j = 0; j < NEXP; j++)
                if (i*128 >= soff[j] && i*128 < soff[j+1]) e = j;
        }
        tile_e[i] = e;
    }
    for (int p = threadIdx.x; p < PADMAX; p += 256) lcode[p] = -1;
}

__global__ void fill_kernel(const int* __restrict__ tki, const float* __restrict__ tkw,
                            const int* __restrict__ off, int* __restrict__ cur,
                            int* __restrict__ lcode, float* __restrict__ lw) {
    int t = blockIdx.x * 256 + threadIdx.x;
    if (t >= T_TOK) return;
    for (int k = 0; k < 2; k++) {
        int e = tki[t*2+k];
        int p = atomicAdd(&cur[e], 1);
        int pos = off[e] + p;
        lcode[pos] = t*2 + k;
        lw[pos] = tkw[t*2+k];
    }
}

// ---- GEMM1: H = silu(A@W1^T) * (A@W3^T) * wt  (A gathered bf16, W fp32->bf16) ----
template<bool ROUTED>
__global__ __launch_bounds__(256, 2)
void gemm1_kernel(const unsigned short* __restrict__ xb,
                  const float* __restrict__ w1b, const float* __restrict__ w3b,
                  unsigned short* __restrict__ H, const int N,
                  const int* __restrict__ list_code, const float* __restrict__ list_w,
                  const int* __restrict__ tile_e) {
    const int K = DMODEL;
    int mt = blockIdx.y, nt = blockIdx.x;
    const float *w1 = w1b, *w3 = w3b;
    if (ROUTED) {
        int e = tile_e[mt];
        if (e < 0) return;
        size_t es = (size_t)N * K;
        w1 += (size_t)e * es; w3 += (size_t)e * es;
    }
    int m0 = mt*128, n0 = nt*128;
    __shared__ alignas(16) unsigned short As[128*40];   // padded stride: 80B = 20 banks
    __shared__ alignas(16) unsigned short B1s[128*40];
    __shared__ alignas(16) unsigned short B3s[128*40];
    __shared__ int   toks[128];
    __shared__ float wts[128];
    int tid = threadIdx.x;
    if (tid < 128) {
        if (ROUTED) {
            int code = list_code[m0 + tid];
            toks[tid] = (code < 0) ? 0 : (code >> 1);
            wts[tid]  = (code < 0) ? 0.f : list_w[m0 + tid];
        } else {
            toks[tid] = m0 + tid; wts[tid] = 1.f;
        }
    }

    f32x4 acc1[4][4], acc2[4][4];
    #pragma unroll
    for (int a = 0; a < 4; a++)
        #pragma unroll
        for (int b = 0; b < 4; b++) {
            acc1[a][b] = (f32x4){0.f,0.f,0.f,0.f};
            acc2[a][b] = (f32x4){0.f,0.f,0.f,0.f};
        }

    int wid = tid >> 6, lane = tid & 63;
    int wm = wid >> 1, wn = wid & 1;
    int ar = wm*64 + (lane & 15);
    int br = wn*64 + (lane & 15);
    int kk = (lane >> 4) * 8;

    for (int k0 = 0; k0 < K; k0 += 32) {
        __syncthreads();
        #pragma unroll
        for (int i = 0; i < 2; i++) {           // A: 128x32 bf16, 16B chunks
            int c = i*256 + tid, row = c >> 2, kc = c & 3;
            const unsigned short* src = xb + (size_t)toks[row]*K + k0 + kc*8;
            *(s16x8*)&As[row*40 + kc*8] = *(const s16x8*)src;
        }
        #pragma unroll
        for (int i = 0; i < 4; i++) {           // B1/B3: 128x32 fp32 -> bf16
            int c = i*256 + tid, row = c >> 3, kc = c & 7;
            size_t g = (size_t)(n0+row)*K + k0 + kc*4;
            float4 v1 = *(const float4*)(w1 + g);
            float4 v3 = *(const float4*)(w3 + g);
            s16x4 o1, o3;
            o1[0]=(short)f2bf(v1.x); o1[1]=(short)f2bf(v1.y); o1[2]=(short)f2bf(v1.z); o1[3]=(short)f2bf(v1.w);
            o3[0]=(short)f2bf(v3.x); o3[1]=(short)f2bf(v3.y); o3[2]=(short)f2bf(v3.z); o3[3]=(short)f2bf(v3.w);
            *(s16x4*)&B1s[row*40 + kc*4] = o1;
            *(s16x4*)&B3s[row*40 + kc*4] = o3;
        }
        __syncthreads();
        s16x8 a[4], b1[4], b3[4];
        #pragma unroll
        for (int f = 0; f < 4; f++) {
            a[f]  = *(const s16x8*)&As [(ar + f*16)*40 + kk];
            b1[f] = *(const s16x8*)&B1s[(br + f*16)*40 + kk];
            b3[f] = *(const s16x8*)&B3s[(br + f*16)*40 + kk];
        }
        #pragma unroll
        for (int mf = 0; mf < 4; mf++)
            #pragma unroll
            for (int nf = 0; nf < 4; nf++) {
                acc1[mf][nf] = __builtin_amdgcn_mfma_f32_16x16x32_bf16(a[mf], b1[nf], acc1[mf][nf], 0,0,0);
                acc2[mf][nf] = __builtin_amdgcn_mfma_f32_16x16x32_bf16(a[mf], b3[nf], acc2[mf][nf], 0,0,0);
            }
    }
    // epilogue: silu(acc1)*acc2*wt -> bf16 H
    #pragma unroll
    for (int mf = 0; mf < 4; mf++) {
        int ib = wm*64 + mf*16 + (lane >> 4)*4;
        #pragma unroll
        for (int nf = 0; nf < 4; nf++) {
            int j = n0 + wn*64 + nf*16 + (lane & 15);
            #pragma unroll
            for (int r = 0; r < 4; r++) {
                int i = ib + r;
                float v1 = acc1[mf][nf][r], v2 = acc2[mf][nf][r];
                float s = v1 / (1.f + __expf(-v1));
                float h = s * v2 * wts[i];
                H[(size_t)(m0+i)*N + j] = f2bf(h);
            }
        }
    }
}

// ---- GEMM2: Y = H @ W2^T ----
template<bool ROUTED>
__global__ __launch_bounds__(256, 2)
void gemm2_kernel(const unsigned short* __restrict__ H, const float* __restrict__ w2b,
                  float* __restrict__ out, float* __restrict__ y, const int K,
                  const int* __restrict__ list_code, const int* __restrict__ tile_e) {
    const int N = DMODEL;
    int mt = blockIdx.y, nt = blockIdx.x;
    const float* w2 = w2b;
    if (ROUTED) {
        int e = tile_e[mt];
        if (e < 0) return;
        w2 += (size_t)e * N * K;
    }
    int m0 = mt*128, n0 = nt*128;
    __shared__ alignas(16) unsigned short As[128*40];
    __shared__ alignas(16) unsigned short Bs[128*40];
    __shared__ int codes[128];
    int tid = threadIdx.x;
    if (ROUTED && tid < 128) codes[tid] = list_code[m0 + tid];

    f32x4 acc[4][4];
    #pragma unroll
    for (int a = 0; a < 4; a++)
        #pragma unroll
        for (int b = 0; b < 4; b++) acc[a][b] = (f32x4){0.f,0.f,0.f,0.f};

    int wid = tid >> 6, lane = tid & 63;
    int wm = wid >> 1, wn = wid & 1;
    int ar = wm*64 + (lane & 15);
    int br = wn*64 + (lane & 15);
    int kk = (lane >> 4) * 8;

    for (int k0 = 0; k0 < K; k0 += 32) {
        __syncthreads();
        #pragma unroll
        for (int i = 0; i < 2; i++) {           // A: H rows (bf16 direct)
            int c = i*256 + tid, row = c >> 2, kc = c & 3;
            const unsigned short* src = H + (size_t)(m0+row)*K + k0 + kc*8;
            *(s16x8*)&As[row*40 + kc*8] = *(const s16x8*)src;
        }
        #pragma unroll
        for (int i = 0; i < 4; i++) {           // B: W2 fp32 -> bf16
            int c = i*256 + tid, row = c >> 3, kc = c & 7;
            size_t g = (size_t)(n0+row)*K + k0 + kc*4;
            float4 v = *(const float4*)(w2 + g);
            s16x4 o;
            o[0]=(short)f2bf(v.x); o[1]=(short)f2bf(v.y); o[2]=(short)f2bf(v.z); o[3]=(short)f2bf(v.w);
            *(s16x4*)&Bs[row*40 + kc*4] = o;
        }
        __syncthreads();
        s16x8 a[4], b[4];
        #pragma unroll
        for (int f = 0; f < 4; f++) {
            a[f] = *(const s16x8*)&As[(ar + f*16)*40 + kk];
            b[f] = *(const s16x8*)&Bs[(br + f*16)*40 + kk];
        }
        #pragma unroll
        for (int mf = 0; mf < 4; mf++)
            #pragma unroll
            for (int nf = 0; nf < 4; nf++)
                acc[mf][nf] = __builtin_amdgcn_mfma_f32_16x16x32_bf16(a[mf], b[nf], acc[mf][nf], 0,0,0);
    }
    #pragma unroll
    for (int mf = 0; mf < 4; mf++) {
        int ib = wm*64 + mf*16 + (lane >> 4)*4;
        #pragma unroll
        for (int nf = 0; nf < 4; nf++) {
            int j = n0 + wn*64 + nf*16 + (lane & 15);
            #pragma unroll
            for (int r = 0; r < 4; r++) {
                int i = ib + r;
                float v = acc[mf][nf][r];
                if (!ROUTED) {
                    out[(size_t)(m0+i)*N + j] = v;
                } else {
                    int code = codes[i];
                    if (code >= 0)
                        y[((size_t)(code & 1)*T_TOK + (code >> 1))*N + j] = v;
                }
            }
        }
    }
}

// ---- combine: out += y0 + y1 ----
__global__ void combine_kernel(float* __restrict__ out, const float* __restrict__ y) {
    size_t i = (size_t)blockIdx.x * 256 + threadIdx.x;   // float4 index
    float4 o = ((const float4*)out)[i];
    float4 a = ((const float4*)y)[i];
    float4 b = ((const float4*)(y + (size_t)T_TOK*DMODEL))[i];
    o.x += a.x + b.x; o.y += a.y + b.y; o.z += a.z + b.z; o.w += a.w + b.w;
    ((float4*)out)[i] = o;
}

extern "C" void kernel_launch(void* const* d_in, const int* in_sizes, int n_in,
                              void* d_out, int out_size, void* d_ws, size_t ws_size,
                              hipStream_t stream) {
    const float* x   = (const float*)d_in[0];
    const float* wg  = (const float*)d_in[1];
    const float* sw1 = (const float*)d_in[2];
    const float* sw3 = (const float*)d_in[3];
    const float* sw2 = (const float*)d_in[4];
    const float* ew1 = (const float*)d_in[5];
    const float* ew3 = (const float*)d_in[6];
    const float* ew2 = (const float*)d_in[7];
    float* out = (float*)d_out;
    char* ws = (char*)d_ws;
    unsigned short* xb = (unsigned short*)(ws + XB_OFF);
    unsigned short* H  = (unsigned short*)(ws + H_OFF);
    float* y = (float*)(ws + Y_OFF);
    char* c = ws + C_OFF;
    int*   cnt    = (int*)  (c + CNT_OFF);
    int*   off    = (int*)  (c + OFF_OFF);
    int*   cur    = (int*)  (c + CUR_OFF);
    int*   tile_e = (int*)  (c + TILEE_OFF);
    int*   tki    = (int*)  (c + TKI_OFF);
    float* tkw    = (float*)(c + TKW_OFF);
    int*   lcode  = (int*)  (c + LCODE_OFF);
    float* lw     = (float*)(c + LW_OFF);

    hipMemsetAsync(cnt, 0, 64, stream);
    cvt_x_kernel<<<8192, 256, 0, stream>>>(x, xb);
    gate_kernel<<<T_TOK, 256, 0, stream>>>(x, wg, tki, tkw, cnt);
    scan_kernel<<<1, 256, 0, stream>>>(cnt, off, cur, tile_e, lcode);
    fill_kernel<<<16, 256, 0, stream>>>(tki, tkw, off, cur, lcode, lw);
    // shared expert
    gemm1_kernel<false><<<dim3(ISH/128, T_TOK/128), 256, 0, stream>>>(
        xb, sw1, sw3, H, ISH, nullptr, nullptr, nullptr);
    gemm2_kernel<false><<<dim3(DMODEL/128, T_TOK/128), 256, 0, stream>>>(
        H, sw2, out, nullptr, ISH, nullptr, nullptr);
    // routed experts (gathered, 128-aligned segments)
    gemm1_kernel<true><<<dim3(IMOE/128, MAXTILES), 256, 0, stream>>>(
        xb, ew1, ew3, H, IMOE, lcode, lw, tile_e);
    gemm2_kernel<true><<<dim3(DMODEL/128, MAXTILES), 256, 0, stream>>>(
        H, ew2, nullptr, y, IMOE, lcode, tile_e);
    combine_kernel<<<8192, 256, 0, stream>>>(out, y);
}